// Round 1
// 81.498 us; speedup vs baseline: 1.0450x; 1.0450x over previous
//
#include <hip/hip_runtime.h>

#define IMG 256
#define TX 64
#define TY 32
#define LH 38          // staged rows: gy0-3 .. gy0+34
#define LSTRIDE 72     // staged cols: gx0-4 .. gx0+67 (16B-aligned both ends)
#define NCHUNK (LH * (LSTRIDE / 4))   // 38*18 = 684 float4 chunks

__device__ __forceinline__ int reflect_idx(int i) {
    // jnp.pad mode="reflect": -1 -> 1, 256 -> 254
    i = i < 0 ? -i : i;
    i = i > (IMG - 1) ? 2 * (IMG - 1) - i : i;
    return i;
}

__device__ __forceinline__ void loadrow(const float* __restrict__ rp, float d[12]) {
    const float4 q0 = *reinterpret_cast<const float4*>(rp);
    const float4 q1 = *reinterpret_cast<const float4*>(rp + 4);
    const float4 q2 = *reinterpret_cast<const float4*>(rp + 8);
    d[0] = q0.x; d[1] = q0.y; d[2]  = q0.z; d[3]  = q0.w;
    d[4] = q1.x; d[5] = q1.y; d[6]  = q1.z; d[7]  = q1.w;
    d[8] = q2.x; d[9] = q2.y; d[10] = q2.z; d[11] = q2.w;
}

__device__ __forceinline__ void fold(const float u[12], const float v[12], float d[12]) {
    #pragma unroll
    for (int j = 0; j < 12; ++j) d[j] = u[j] + v[j];
}

// horizontal weighted sum over a 12-float row segment; pixel p uses indices p+1..p+7
__device__ __forceinline__ float rsum(const float v[12], int p,
                                      const float e1[4], const float e2[4],
                                      const float e3[4]) {
    return v[p + 4]
         + e1[p] * (v[p + 3] + v[p + 5])
         + e2[p] * (v[p + 2] + v[p + 6])
         + e3[p] * (v[p + 1] + v[p + 7]);
}

__global__ __launch_bounds__(256)
void agf_kernel(const float* __restrict__ x, const float* __restrict__ sigma,
                float* __restrict__ out) {
    __shared__ float tile[LH * LSTRIDE];

    const int plane = blockIdx.z;                 // b*C + c, 0..47
    const int gx0 = blockIdx.x * TX;
    const int gy0 = blockIdx.y * TY;
    const int tid = threadIdx.x;

    const float* xp = x + (size_t)plane * (IMG * IMG);

    // ---- stage x tile into LDS: float4 chunks, local col lc <-> global gx0-4+lc ----
    #pragma unroll
    for (int it = 0; it < 3; ++it) {
        const int idx = tid + it * 256;
        if (idx < NCHUNK) {
            const int lr = idx / 18;              // chunk row
            const int lc4 = idx - lr * 18;
            const int lcol = lc4 * 4;
            const int grow = reflect_idx(gy0 - 3 + lr);
            const int gcol = gx0 - 4 + lcol;
            const float* src = xp + (size_t)grow * IMG;
            if (gcol >= 0 && gcol <= IMG - 4) {   // aligned vector fast path
                *reinterpret_cast<float4*>(&tile[lr * LSTRIDE + lcol]) =
                    *reinterpret_cast<const float4*>(src + gcol);
            } else {                              // edge chunks: per-element reflect
                #pragma unroll
                for (int j = 0; j < 4; ++j)
                    tile[lr * LSTRIDE + lcol + j] = src[reflect_idx(gcol + j)];
            }
        }
    }
    __syncthreads();

    // ---- each thread computes a 4-wide x 2-row pixel patch ----
    // two adjacent output rows share 6 of their 8 input rows -> 24 ds_read_b128
    // per 8 pixels (3/px) instead of 42 (5.25/px).
    const int tx = tid & 15;            // 0..15
    const int ty = (tid >> 4) * 2;      // 0,2,..,30: first output row in tile
    const int col0 = tx * 4;            // pixel p: global col gx0+col0+p, local col0+p+4
    const int gy = gy0 + ty;
    const size_t gbase = (size_t)plane * (IMG * IMG) + (size_t)gy * IMG + gx0 + col0;

    const float4 sg0 = *reinterpret_cast<const float4*>(sigma + gbase);
    const float4 sg1 = *reinterpret_cast<const float4*>(sigma + gbase + IMG);
    const float s0v[4] = {sg0.x, sg0.y, sg0.z, sg0.w};
    const float s1v[4] = {sg1.x, sg1.y, sg1.z, sg1.w};

    // per-pixel weights: a = exp(-s^2/2); e1=a, e2=a^4, e3=a^9; norm = 1/S^2
    float e1a[4], e2a[4], e3a[4], inva[4];
    float e1b[4], e2b[4], e3b[4], invb[4];
    #pragma unroll
    for (int p = 0; p < 4; ++p) {
        {
            const float s2 = s0v[p] * s0v[p];
            const float a = __expf(-0.5f * s2);
            const float t = a * a;
            const float b = t * t;                // a^4
            const float c = b * b * a;            // a^9
            e1a[p] = a; e2a[p] = b; e3a[p] = c;
            const float S = 1.0f + 2.0f * (a + b + c);
            inva[p] = __builtin_amdgcn_rcpf(S * S);
        }
        {
            const float s2 = s1v[p] * s1v[p];
            const float a = __expf(-0.5f * s2);
            const float t = a * a;
            const float b = t * t;
            const float c = b * b * a;
            e1b[p] = a; e2b[p] = b; e3b[p] = c;
            const float S = 1.0f + 2.0f * (a + b + c);
            invb[p] = __builtin_amdgcn_rcpf(S * S);
        }
    }

    // input rows (tile coords): out0 uses ty..ty+6 (center ty+3),
    //                           out1 uses ty+1..ty+7 (center ty+4).
    // pair map: out0: (R0,R6)e3a (R1,R5)e2a (R2,R4)e1a  center R3
    //           out1: (R1,R7)e3b (R2,R6)e2b (R3,R5)e1b  center R4
    const float* tbase = &tile[ty * LSTRIDE + col0];

    float acc0[4] = {0.f, 0.f, 0.f, 0.f};
    float acc1[4] = {0.f, 0.f, 0.f, 0.f};
    float ra[12], rb[12], rc[12], rf[12];

    // 1. R1 + R7 -> out1, e3b          (keep R1 in ra)
    loadrow(tbase + 1 * LSTRIDE, ra);
    loadrow(tbase + 7 * LSTRIDE, rb);
    fold(ra, rb, rf);
    #pragma unroll
    for (int p = 0; p < 4; ++p) acc1[p] += e3b[p] * rsum(rf, p, e1b, e2b, e3b);

    // 2. R1 + R5 -> out0, e2a          (keep R5 in rb)
    loadrow(tbase + 5 * LSTRIDE, rb);
    fold(ra, rb, rf);
    #pragma unroll
    for (int p = 0; p < 4; ++p) acc0[p] += e2a[p] * rsum(rf, p, e1a, e2a, e3a);

    // 3. R3 + R5 -> out1, e1b          (keep R3 in ra for out0 center)
    loadrow(tbase + 3 * LSTRIDE, ra);
    fold(ra, rb, rf);
    #pragma unroll
    for (int p = 0; p < 4; ++p) acc1[p] += e1b[p] * rsum(rf, p, e1b, e2b, e3b);

    // 4. R0 + R6 -> out0, e3a          (keep R6 in rc)
    loadrow(tbase + 0 * LSTRIDE, rb);
    loadrow(tbase + 6 * LSTRIDE, rc);
    fold(rb, rc, rf);
    #pragma unroll
    for (int p = 0; p < 4; ++p) acc0[p] += e3a[p] * rsum(rf, p, e1a, e2a, e3a);

    // 5. R2 + R6 -> out1, e2b          (keep R2 in rb)
    loadrow(tbase + 2 * LSTRIDE, rb);
    fold(rb, rc, rf);
    #pragma unroll
    for (int p = 0; p < 4; ++p) acc1[p] += e2b[p] * rsum(rf, p, e1b, e2b, e3b);

    // 6. R2 + R4 -> out0, e1a          (keep R4 in rc for out1 center)
    loadrow(tbase + 4 * LSTRIDE, rc);
    fold(rb, rc, rf);
    #pragma unroll
    for (int p = 0; p < 4; ++p) acc0[p] += e1a[p] * rsum(rf, p, e1a, e2a, e3a);

    // 7. centers: R3 -> out0, R4 -> out1 (weight 1)
    #pragma unroll
    for (int p = 0; p < 4; ++p) acc0[p] += rsum(ra, p, e1a, e2a, e3a);
    #pragma unroll
    for (int p = 0; p < 4; ++p) acc1[p] += rsum(rc, p, e1b, e2b, e3b);

    float4 o0, o1;
    o0.x = acc0[0] * inva[0]; o0.y = acc0[1] * inva[1];
    o0.z = acc0[2] * inva[2]; o0.w = acc0[3] * inva[3];
    o1.x = acc1[0] * invb[0]; o1.y = acc1[1] * invb[1];
    o1.z = acc1[2] * invb[2]; o1.w = acc1[3] * invb[3];
    *reinterpret_cast<float4*>(out + gbase) = o0;
    *reinterpret_cast<float4*>(out + gbase + IMG) = o1;
}

extern "C" void kernel_launch(void* const* d_in, const int* in_sizes, int n_in,
                              void* d_out, int out_size, void* d_ws, size_t ws_size,
                              hipStream_t stream) {
    const float* x = (const float*)d_in[0];
    const float* sigma = (const float*)d_in[1];
    float* out = (float*)d_out;

    const int planes = in_sizes[0] / (IMG * IMG);   // 16*3 = 48
    dim3 grid(IMG / TX, IMG / TY, planes);          // (4, 8, 48)
    agf_kernel<<<grid, 256, 0, stream>>>(x, sigma, out);
}